// Round 1
// baseline (14140.570 us; speedup 1.0000x reference)
//
#include <hip/hip_runtime.h>

// Decoder GRU, B=128 T=512 X=64 H=256, skip=4.  Persistent cooperative kernel,
// one grid barrier per step.  128 WGs x 256 thr: WG = 16 batches x 16 h-cols,
// one h_new element per thread (fp32 VALU).  h history in 16-slot ring (d_ws),
// x_prev fed back through d_out itself.
constexpr int B_ = 128;
constexpr int T_ = 512;
constexpr int X_ = 64;
constexpr int H_ = 256;
constexpr int NWG = 128;
constexpr int NT = 256;
constexpr int RS = 16;  // ring slots; OK for skip <= 7 (refs reach 2*skip back)

__device__ __forceinline__ float sigmoid_f(float x) {
  float e = __expf(fminf(-x, 80.f));
  return 1.f / (1.f + e);
}
__device__ __forceinline__ float tanh_f(float x) {
  float e = __expf(fminf(-2.f * x, 80.f));   // clamp: exp(80) finite in fp32
  return (1.f - e) / (1.f + e);
}

// Flag-array grid barrier: per-WG release store (no same-address atomic
// serialization), WG0 aggregates, everyone spins relaxed on gen then does one
// acquire + threadfence (device scope -> safe across non-coherent XCD L2s).
__device__ __forceinline__ void grid_sync(int* gen, int* flags, int target) {
  __syncthreads();
  if (threadIdx.x == 0) {
    __threadfence();
    __hip_atomic_store(&flags[blockIdx.x], target, __ATOMIC_RELEASE,
                       __HIP_MEMORY_SCOPE_AGENT);
  }
  if (blockIdx.x == 0) {
    if (threadIdx.x < NWG) {
      while (__hip_atomic_load(&flags[threadIdx.x], __ATOMIC_RELAXED,
                               __HIP_MEMORY_SCOPE_AGENT) < target)
        __builtin_amdgcn_s_sleep(1);
    }
    __syncthreads();
    if (threadIdx.x == 0)
      __hip_atomic_store(gen, target, __ATOMIC_RELEASE,
                         __HIP_MEMORY_SCOPE_AGENT);
  }
  if (threadIdx.x == 0) {
    while (__hip_atomic_load(gen, __ATOMIC_RELAXED,
                             __HIP_MEMORY_SCOPE_AGENT) < target)
      __builtin_amdgcn_s_sleep(1);
    (void)__hip_atomic_load(gen, __ATOMIC_ACQUIRE, __HIP_MEMORY_SCOPE_AGENT);
    __threadfence();
  }
  __syncthreads();
}

__global__ __launch_bounds__(NT, 2) void decoder_kernel(
    const float* __restrict__ h_enc, const float* __restrict__ W_ih,
    const float* __restrict__ W_hh, const float* __restrict__ b_ih,
    const float* __restrict__ b_hh, const float* __restrict__ W_out,
    const float* __restrict__ b_out, const int* __restrict__ mask0,
    const int* __restrict__ mask1, const int* __restrict__ skipp,
    float* __restrict__ out, float* __restrict__ ring, int* gen, int* flags) {
  __shared__ float hid[16][260];  // masked hidden tile, pad 260 (bank-safe)
  __shared__ float pt[16][260];   // h_prev + skip_p tile (for projection)
  __shared__ float xt[16][68];    // x_prev tile

  const int t = threadIdx.x;
  const int wg = blockIdx.x;
  const int b_blk = wg >> 4;  // 8 blocks of 16 batches
  const int c_blk = wg & 15;  // 16 blocks of 16 h-cols (and 4 x-cols)
  const int gb = b_blk * 16;
  const int skip = skipp[0];

  // hl = t>>4 so each wave owns disjoint weight rows (no cross-wave refetch)
  const int hl = t >> 4;  // 0..15 h-col within tile
  const int bl = t & 15;  // 0..15 batch within tile
  const int hcg = c_blk * 16 + hl;
  const int bg = gb + bl;

  const float4* whr = ((const float4*)W_hh) + (size_t)(0 * H_ + hcg) * (H_ / 4);
  const float4* whz = ((const float4*)W_hh) + (size_t)(1 * H_ + hcg) * (H_ / 4);
  const float4* whn = ((const float4*)W_hh) + (size_t)(2 * H_ + hcg) * (H_ / 4);
  const float4* wir = ((const float4*)W_ih) + (size_t)(0 * H_ + hcg) * (X_ / 4);
  const float4* wiz = ((const float4*)W_ih) + (size_t)(1 * H_ + hcg) * (X_ / 4);
  const float4* win = ((const float4*)W_ih) + (size_t)(2 * H_ + hcg) * (X_ / 4);
  const float bsr = b_ih[hcg] + b_hh[hcg];
  const float bsz = b_ih[H_ + hcg] + b_hh[H_ + hcg];
  const float bin_ = b_ih[2 * H_ + hcg];
  const float bhn_ = b_hh[2 * H_ + hcg];

  int bt = 0;  // barrier generation target

  for (int i = 0; i < T_; ++i) {
    const float m0 = (float)mask0[i];
    const float m1 = (float)mask1[i];
    const int pg = (i < skip) ? 2 * i : i - skip;
    const bool gzf = pg < skip;
    const int gidx = (pg - skip > 0) ? (pg - skip) : 0;
    const int pp = (i < skip) ? 2 * i + 1 : i - skip;
    const bool pzf = pp < skip;
    const int pidx = (pp - skip > 0) ? (pp - skip) : 0;
    const bool late_p = (!pzf) && (pidx == i);  // skip_p needs this step's h

    const float* hprev =
        (i == 0) ? h_enc : ring + (size_t)((i - 1) & (RS - 1)) * B_ * H_;
    const float* gsrc = ring + (size_t)(gidx & (RS - 1)) * B_ * H_;
    const float* psrc = ring + (size_t)(pidx & (RS - 1)) * B_ * H_;

    // ---- stage LDS tiles (coalesced) ----
#pragma unroll
    for (int j = 0; j < 16; ++j) {
      int idx = t + NT * j;
      int bb = idx >> 8, k = idx & 255;
      size_t off = (size_t)(gb + bb) * H_ + k;
      float hp = hprev[off];
      float sg = gzf ? 0.f : gsrc[off];
      hid[bb][k] = m0 * hp + m1 * sg;
      if (!late_p) {
        float sp = pzf ? 0.f : psrc[off];
        pt[bb][k] = hp + sp;
      }
    }
#pragma unroll
    for (int j = 0; j < 4; ++j) {
      int idx = t + NT * j;
      int bb = idx >> 6, xx = idx & 63;
      xt[bb][xx] = (i == 0) ? 0.f
                            : out[(size_t)(gb + bb) * T_ * X_ +
                                  (size_t)(i - 1) * X_ + xx];
    }
    __syncthreads();

    // ---- GRU cell: one (b,h) element per thread ----
    float ar = 0.f, az = 0.f, an = 0.f;
    const float4* hrow = (const float4*)&hid[bl][0];
#pragma unroll 4
    for (int k4 = 0; k4 < H_ / 4; ++k4) {
      float4 h4 = hrow[k4];
      float4 r4 = whr[k4];
      float4 z4 = whz[k4];
      float4 n4 = whn[k4];
      ar = fmaf(h4.w, r4.w, fmaf(h4.z, r4.z, fmaf(h4.y, r4.y, fmaf(h4.x, r4.x, ar))));
      az = fmaf(h4.w, z4.w, fmaf(h4.z, z4.z, fmaf(h4.y, z4.y, fmaf(h4.x, z4.x, az))));
      an = fmaf(h4.w, n4.w, fmaf(h4.z, n4.z, fmaf(h4.y, n4.y, fmaf(h4.x, n4.x, an))));
    }
    float gr = 0.f, gzv = 0.f, gn = 0.f;
    const float4* xrow = (const float4*)&xt[bl][0];
#pragma unroll
    for (int k4 = 0; k4 < X_ / 4; ++k4) {
      float4 x4 = xrow[k4];
      float4 r4 = wir[k4];
      float4 z4 = wiz[k4];
      float4 n4 = win[k4];
      gr = fmaf(x4.w, r4.w, fmaf(x4.z, r4.z, fmaf(x4.y, r4.y, fmaf(x4.x, r4.x, gr))));
      gzv = fmaf(x4.w, z4.w, fmaf(x4.z, z4.z, fmaf(x4.y, z4.y, fmaf(x4.x, z4.x, gzv))));
      gn = fmaf(x4.w, n4.w, fmaf(x4.z, n4.z, fmaf(x4.y, n4.y, fmaf(x4.x, n4.x, gn))));
    }
    float r = sigmoid_f(gr + ar + bsr);
    float z = sigmoid_f(gzv + az + bsz);
    float n = tanh_f((gn + bin_) + r * (an + bhn_));
    float hv = hid[bl][hcg];
    float hnew = fmaf(z, hv - n, n);  // (1-z)*n + z*hv
    ring[(size_t)(i & (RS - 1)) * B_ * H_ + (size_t)bg * H_ + hcg] = hnew;

    if (late_p) {  // i == skip-1: skip_p = this step's h_new
      grid_sync(gen, flags, ++bt);
#pragma unroll
      for (int j = 0; j < 16; ++j) {
        int idx = t + NT * j;
        int bb = idx >> 8, k = idx & 255;
        size_t off = (size_t)(gb + bb) * H_ + k;
        pt[bb][k] = hprev[off] + psrc[off];
      }
      __syncthreads();
    }

    // ---- output projection: 16 batches x 4 x-cols on threads 0..63 ----
    if (t < 64) {
      int obl = t >> 2, xl = t & 3;
      int xg = c_blk * 4 + xl;
      const float4* prow = (const float4*)&pt[obl][0];
      const float4* wo = ((const float4*)W_out) + (size_t)xg * (H_ / 4);
      float acc = 0.f;
#pragma unroll 4
      for (int k4 = 0; k4 < H_ / 4; ++k4) {
        float4 p4 = prow[k4];
        float4 w4 = wo[k4];
        acc = fmaf(p4.w, w4.w, fmaf(p4.z, w4.z, fmaf(p4.y, w4.y, fmaf(p4.x, w4.x, acc))));
      }
      out[(size_t)(gb + obl) * T_ * X_ + (size_t)i * X_ + xg] = acc + b_out[xg];
    }

    grid_sync(gen, flags, ++bt);  // publish h_new + out_i for step i+1
  }
}

extern "C" void kernel_launch(void* const* d_in, const int* in_sizes, int n_in,
                              void* d_out, int out_size, void* d_ws,
                              size_t ws_size, hipStream_t stream) {
  (void)in_sizes; (void)n_in; (void)out_size; (void)ws_size;
  // d_in[0] = input [B,T,X] — unused by the reference computation.
  const float* h_enc = (const float*)d_in[1];
  const float* W_ih = (const float*)d_in[2];
  const float* W_hh = (const float*)d_in[3];
  const float* b_ih = (const float*)d_in[4];
  const float* b_hh = (const float*)d_in[5];
  const float* W_out = (const float*)d_in[6];
  const float* b_out = (const float*)d_in[7];
  const int* mask0 = (const int*)d_in[8];
  const int* mask1 = (const int*)d_in[9];
  const int* skipp = (const int*)d_in[10];
  float* out = (float*)d_out;

  int* gen = (int*)d_ws;                          // [0..4KB): barrier state
  int* flags = (int*)((char*)d_ws + 128);         // NWG arrival flags
  float* ring = (float*)((char*)d_ws + 4096);     // 16*B*H fp32 = 2 MB

  hipMemsetAsync(d_ws, 0, 4096, stream);          // ws is 0xAA-poisoned

  void* args[] = {&h_enc, &W_ih, &W_hh, &b_ih, &b_hh, &W_out, &b_out,
                  &mask0, &mask1, &skipp, &out, &ring, &gen, &flags};
  hipError_t err = hipLaunchCooperativeKernel(
      (void*)decoder_kernel, dim3(NWG), dim3(NT), args, 0, stream);
  if (err != hipSuccess) {
    // Fallback: 128 WGs on 256 CUs are trivially co-resident.
    decoder_kernel<<<dim3(NWG), dim3(NT), 0, stream>>>(
        h_enc, W_ih, W_hh, b_ih, b_hh, W_out, b_out, mask0, mask1, skipp, out,
        ring, gen, flags);
  }
}

// Round 2
// 11463.633 us; speedup vs baseline: 1.2335x; 1.2335x over previous
//
#include <hip/hip_runtime.h>

// Decoder GRU, B=128 T=512 X=64 H=256, skip=4.  Persistent kernel, 128 WGs x
// 256 thr.  WG = 16 batches x 16 h-cols, one h element per thread (fp32 VALU).
// Sync is GROUP-LOCAL: only the 16 WGs sharing a batch-block communicate
// (GRU mixes over H, never over B), via a fence-free single-hop flag barrier.
// All cross-WG data uses relaxed agent-scope atomics (cache-bypass to the
// coherence point) -> no buffer_wbl2/buffer_inv storms, L1/L2 stay warm for
// the weights.  h history in a 16-slot ring (d_ws); x_prev fed back via d_out.
constexpr int B_ = 128;
constexpr int T_ = 512;
constexpr int X_ = 64;
constexpr int H_ = 256;
constexpr int NWG = 128;
constexpr int NT = 256;
constexpr int RS = 16;   // ring slots; lookback is 2*skip, OK for skip <= 7
constexpr int GSZ = 16;  // WGs per sync group (one batch-block)

__device__ __forceinline__ float sigmoid_f(float x) {
  float e = __expf(fminf(-x, 80.f));
  return 1.f / (1.f + e);
}
__device__ __forceinline__ float tanh_f(float x) {
  float e = __expf(fminf(-2.f * x, 80.f));
  return (1.f - e) / (1.f + e);
}

#define ALOADF(p) \
  __hip_atomic_load((float*)(p), __ATOMIC_RELAXED, __HIP_MEMORY_SCOPE_AGENT)
#define ASTOREF(p, v) \
  __hip_atomic_store((float*)(p), (v), __ATOMIC_RELAXED, __HIP_MEMORY_SCOPE_AGENT)

// Fence-free single-hop group barrier.  Every wave drains its own global
// stores (vmcnt ack for agent-scope stores = visible at coherence point),
// then member 0-thread stores its flag; 16 threads poll the 16 member flags.
// No buffer_wbl2 / buffer_inv: communicated data never lives dirty in L2.
__device__ __forceinline__ void group_sync(int* gflags, int member, int target) {
  asm volatile("s_waitcnt vmcnt(0)" ::: "memory");
  __syncthreads();
  if (threadIdx.x == 0)
    __hip_atomic_store(&gflags[member], target, __ATOMIC_RELAXED,
                       __HIP_MEMORY_SCOPE_AGENT);
  if (threadIdx.x < GSZ) {
    while (__hip_atomic_load(&gflags[threadIdx.x], __ATOMIC_RELAXED,
                             __HIP_MEMORY_SCOPE_AGENT) < target)
      __builtin_amdgcn_s_sleep(1);
  }
  __syncthreads();
}

__global__ __launch_bounds__(NT, 2) void decoder_kernel(
    const float* __restrict__ h_enc, const float* __restrict__ W_ih,
    const float* __restrict__ W_hh, const float* __restrict__ b_ih,
    const float* __restrict__ b_hh, const float* __restrict__ W_out,
    const float* __restrict__ b_out, const int* __restrict__ mask0,
    const int* __restrict__ mask1, const int* __restrict__ skipp,
    float* __restrict__ out, float* __restrict__ ring, int* flags) {
  __shared__ float hid[16][260];   // masked hidden tile (pad: bank-safe)
  __shared__ float pt[16][260];    // h_prev + skip_p tile (projection input)
  __shared__ float xt[16][68];     // x_prev tile
  __shared__ float nt_t[16][17];   // h_new bounce tile for coalesced ring store

  const int t = threadIdx.x;
  const int wg = blockIdx.x;
  const int b_blk = wg & 7;   // group id; blockIdx%8 ~ XCD (locality heuristic)
  const int c_blk = wg >> 3;  // member 0..15: 16 h-cols (and 4 x-cols)
  const int gb = b_blk * 16;
  const int skip = skipp[0];
  int* gflags = flags + b_blk * GSZ;

  const int hl = t >> 4;  // h-col within tile; wave owns disjoint weight rows
  const int bl = t & 15;  // batch within tile
  const int hcg = c_blk * 16 + hl;

  const float4* whr = ((const float4*)W_hh) + (size_t)(0 * H_ + hcg) * (H_ / 4);
  const float4* whz = ((const float4*)W_hh) + (size_t)(1 * H_ + hcg) * (H_ / 4);
  const float4* whn = ((const float4*)W_hh) + (size_t)(2 * H_ + hcg) * (H_ / 4);
  const float4* wir = ((const float4*)W_ih) + (size_t)(0 * H_ + hcg) * (X_ / 4);
  const float4* wiz = ((const float4*)W_ih) + (size_t)(1 * H_ + hcg) * (X_ / 4);
  const float4* win = ((const float4*)W_ih) + (size_t)(2 * H_ + hcg) * (X_ / 4);
  const float bsr = b_ih[hcg] + b_hh[hcg];
  const float bsz = b_ih[H_ + hcg] + b_hh[H_ + hcg];
  const float bin_ = b_ih[2 * H_ + hcg];
  const float bhn_ = b_hh[2 * H_ + hcg];

  int bt = 0;  // barrier generation (uniform across all WGs)

  for (int i = 0; i < T_; ++i) {
    const float m0 = (float)mask0[i];
    const float m1 = (float)mask1[i];
    const int pg = (i < skip) ? 2 * i : i - skip;
    const bool gzf = pg < skip;
    const int gidx = (pg - skip > 0) ? (pg - skip) : 0;
    const int pp = (i < skip) ? 2 * i + 1 : i - skip;
    const bool pzf = pp < skip;
    const int pidx = (pp - skip > 0) ? (pp - skip) : 0;
    const bool late_p = (!pzf) && (pidx == i);  // i == skip-1 only

    const float* hprev =
        (i == 0) ? h_enc : ring + (size_t)((i - 1) & (RS - 1)) * B_ * H_;
    const float* gsrc = ring + (size_t)(gidx & (RS - 1)) * B_ * H_;
    const float* psrc = ring + (size_t)(pidx & (RS - 1)) * B_ * H_;

    // ---- stage LDS tiles (coalesced, cache-bypassing loads) ----
#pragma unroll
    for (int j = 0; j < 16; ++j) {
      int idx = t + NT * j;
      int bb = idx >> 8, k = idx & 255;
      size_t off = (size_t)(gb + bb) * H_ + k;
      float hp = ALOADF(&hprev[off]);
      float sg = gzf ? 0.f : ALOADF(&gsrc[off]);
      hid[bb][k] = m0 * hp + m1 * sg;
      if (!late_p) {
        float sp = pzf ? 0.f : ALOADF(&psrc[off]);
        pt[bb][k] = hp + sp;
      }
    }
#pragma unroll
    for (int j = 0; j < 4; ++j) {
      int idx = t + NT * j;
      int bb = idx >> 6, xx = idx & 63;
      xt[bb][xx] = (i == 0) ? 0.f
                            : ALOADF(&out[(size_t)(gb + bb) * T_ * X_ +
                                          (size_t)(i - 1) * X_ + xx]);
    }
    __syncthreads();

    // ---- GRU cell: one (b,h) element per thread ----
    float ar = 0.f, az = 0.f, an = 0.f;
    const float4* hrow = (const float4*)&hid[bl][0];
#pragma unroll 4
    for (int k4 = 0; k4 < H_ / 4; ++k4) {
      float4 h4 = hrow[k4];
      float4 r4 = whr[k4];
      float4 z4 = whz[k4];
      float4 n4 = whn[k4];
      ar = fmaf(h4.w, r4.w, fmaf(h4.z, r4.z, fmaf(h4.y, r4.y, fmaf(h4.x, r4.x, ar))));
      az = fmaf(h4.w, z4.w, fmaf(h4.z, z4.z, fmaf(h4.y, z4.y, fmaf(h4.x, z4.x, az))));
      an = fmaf(h4.w, n4.w, fmaf(h4.z, n4.z, fmaf(h4.y, n4.y, fmaf(h4.x, n4.x, an))));
    }
    float gr = 0.f, gzv = 0.f, gn = 0.f;
    const float4* xrow = (const float4*)&xt[bl][0];
#pragma unroll
    for (int k4 = 0; k4 < X_ / 4; ++k4) {
      float4 x4 = xrow[k4];
      float4 r4 = wir[k4];
      float4 z4 = wiz[k4];
      float4 n4 = win[k4];
      gr = fmaf(x4.w, r4.w, fmaf(x4.z, r4.z, fmaf(x4.y, r4.y, fmaf(x4.x, r4.x, gr))));
      gzv = fmaf(x4.w, z4.w, fmaf(x4.z, z4.z, fmaf(x4.y, z4.y, fmaf(x4.x, z4.x, gzv))));
      gn = fmaf(x4.w, n4.w, fmaf(x4.z, n4.z, fmaf(x4.y, n4.y, fmaf(x4.x, n4.x, gn))));
    }
    float r = sigmoid_f(gr + ar + bsr);
    float z = sigmoid_f(gzv + az + bsz);
    float n = tanh_f((gn + bin_) + r * (an + bhn_));
    float hv = hid[bl][hcg];
    float hnew = fmaf(z, hv - n, n);  // (1-z)*n + z*hv

    // ---- bounce h_new through LDS, store ring coalesced (16x64B chunks) ----
    nt_t[bl][hl] = hnew;
    __syncthreads();
    {
      int bb = t >> 4, k = t & 15;
      ASTOREF(&ring[(size_t)(i & (RS - 1)) * B_ * H_ + (size_t)(gb + bb) * H_ +
                    c_blk * 16 + k],
              nt_t[bb][k]);
    }

    if (late_p) {  // i == skip-1: skip_p = this step's h_new
      group_sync(gflags, c_blk, ++bt);
#pragma unroll
      for (int j = 0; j < 16; ++j) {
        int idx = t + NT * j;
        int bb = idx >> 8, k = idx & 255;
        size_t off = (size_t)(gb + bb) * H_ + k;
        pt[bb][k] = ALOADF(&hprev[off]) + ALOADF(&psrc[off]);
      }
      __syncthreads();
    }

    // ---- output projection: 16 batches x 4 x-cols on threads 0..63 ----
    if (t < 64) {
      int obl = t >> 2, xl = t & 3;
      int xg = c_blk * 4 + xl;
      const float4* prow = (const float4*)&pt[obl][0];
      const float4* wo = ((const float4*)W_out) + (size_t)xg * (H_ / 4);
      float acc = 0.f;
#pragma unroll 4
      for (int k4 = 0; k4 < H_ / 4; ++k4) {
        float4 p4 = prow[k4];
        float4 w4 = wo[k4];
        acc = fmaf(p4.w, w4.w, fmaf(p4.z, w4.z, fmaf(p4.y, w4.y, fmaf(p4.x, w4.x, acc))));
      }
      ASTOREF(&out[(size_t)(gb + obl) * T_ * X_ + (size_t)i * X_ + xg],
              acc + b_out[xg]);
    }

    group_sync(gflags, c_blk, ++bt);  // publish h_new + out_i for step i+1
  }
}

extern "C" void kernel_launch(void* const* d_in, const int* in_sizes, int n_in,
                              void* d_out, int out_size, void* d_ws,
                              size_t ws_size, hipStream_t stream) {
  (void)in_sizes; (void)n_in; (void)out_size; (void)ws_size;
  // d_in[0] = input [B,T,X] — unused by the reference computation.
  const float* h_enc = (const float*)d_in[1];
  const float* W_ih = (const float*)d_in[2];
  const float* W_hh = (const float*)d_in[3];
  const float* b_ih = (const float*)d_in[4];
  const float* b_hh = (const float*)d_in[5];
  const float* W_out = (const float*)d_in[6];
  const float* b_out = (const float*)d_in[7];
  const int* mask0 = (const int*)d_in[8];
  const int* mask1 = (const int*)d_in[9];
  const int* skipp = (const int*)d_in[10];
  float* out = (float*)d_out;

  int* flags = (int*)d_ws;                      // 8 groups x 16 member flags
  float* ring = (float*)((char*)d_ws + 4096);   // 16*B*H fp32 = 2 MB

  hipMemsetAsync(d_ws, 0, 4096, stream);        // ws is 0xAA-poisoned

  // 128 WGs (<=1 per CU) are trivially co-resident; groups of 16 WGs only
  // sync among themselves, so no cooperative launch is required.
  decoder_kernel<<<dim3(NWG), dim3(NT), 0, stream>>>(
      h_enc, W_ih, W_hh, b_ih, b_hh, W_out, b_out, mask0, mask1, skipp, out,
      ring, flags);
}

// Round 3
// 8758.359 us; speedup vs baseline: 1.6145x; 1.3089x over previous
//
#include <hip/hip_runtime.h>

// Decoder GRU, B=128 T=512 X=64 H=256, skip=4 (runtime).
// Round 3: ZERO inter-WG communication.  64 WGs x 256 thr; each WG owns 2
// batches end-to-end.  All recurrent state (h ring, hidden, proj input, x
// feedback) lives in LDS -> no atomics/fences/flags at all.  Each CU streams
// the full weight set per step from its XCD L2; a prep kernel transposes the
// weights to k4-major [k4][row] float4 layout in d_ws so every weight load is
// 64 lanes x 16 B fully contiguous (exact-compulsory 1 MB/step/CU, no L1
// thrash).  Expected regime: L2->CU bandwidth bound, ~3.4 us/step.
constexpr int B_ = 128;
constexpr int T_ = 512;
constexpr int X_ = 64;
constexpr int H_ = 256;
constexpr int NWG = 64;   // 2 batches per WG
constexpr int NT = 256;
constexpr int RS = 16;    // ring slots; lookback 2*skip, OK for skip <= 7

constexpr int F4_HH = 64 * 768;   // 49152 float4 (768 KB)
constexpr int F4_IH = 16 * 768;   // 12288 float4 (192 KB)
constexpr int F4_OUT = 64 * 64;   //  4096 float4 (64 KB)
constexpr int F4_TOTAL = F4_HH + F4_IH + F4_OUT;  // 65536 -> 1 MB in d_ws

__device__ __forceinline__ float sigmoid_f(float x) {
  float e = __expf(fminf(-x, 80.f));
  return 1.f / (1.f + e);
}
__device__ __forceinline__ float tanh_f(float x) {
  float e = __expf(fminf(-2.f * x, 80.f));
  return (1.f - e) / (1.f + e);
}
__device__ __forceinline__ float dot4(float4 a, float4 b, float acc) {
  acc = fmaf(a.x, b.x, acc);
  acc = fmaf(a.y, b.y, acc);
  acc = fmaf(a.z, b.z, acc);
  acc = fmaf(a.w, b.w, acc);
  return acc;
}

// One-time layout transform: T_hh[k4*768 + r] = W_hh[r][4k4..4k4+3], etc.
// Makes the main kernel's weight loads 64-lane contiguous (1 KB/instr).
__global__ void prep_kernel(const float4* __restrict__ Wih,
                            const float4* __restrict__ Whh,
                            const float4* __restrict__ Wout,
                            float4* __restrict__ T) {
  int id = blockIdx.x * NT + threadIdx.x;
  if (id < F4_HH) {
    int k4 = id / 768, r = id - k4 * 768;
    T[id] = Whh[r * (H_ / 4) + k4];
  } else if (id < F4_HH + F4_IH) {
    int j = id - F4_HH;
    int k4 = j / 768, r = j - k4 * 768;
    T[id] = Wih[r * (X_ / 4) + k4];
  } else if (id < F4_TOTAL) {
    int j = id - F4_HH - F4_IH;
    int k4 = j >> 6, c = j & 63;
    T[id] = Wout[c * (H_ / 4) + k4];
  }
}

__global__ __launch_bounds__(NT, 1) void decoder_kernel(
    const float* __restrict__ h_enc, const float* __restrict__ b_ih,
    const float* __restrict__ b_hh, const float* __restrict__ b_out,
    const int* __restrict__ mask0, const int* __restrict__ mask1,
    const int* __restrict__ skipp, const float4* __restrict__ T,
    float* __restrict__ out) {
  __shared__ float ring[2][RS][H_];  // 32 KB: WG-private h history
  __shared__ float hid[2][H_];       // masked hidden (GRU input)
  __shared__ float pt[2][H_];        // h_prev + skip_p (projection input)
  __shared__ float xt[2][X_];        // x feedback (= previous out row)
  __shared__ float pp[2][2][X_];     // projection k-half partials

  const int t = threadIdx.x;         // = h column
  const int b0 = blockIdx.x * 2;
  const int skip = skipp[0];
  const float4* Thh = T;
  const float4* Tih = T + F4_HH;
  const float4* Tou = T + F4_HH + F4_IH;

  const float bsr = b_ih[t] + b_hh[t];
  const float bsz = b_ih[H_ + t] + b_hh[H_ + t];
  const float bin_ = b_ih[2 * H_ + t];
  const float bhn_ = b_hh[2 * H_ + t];

  if (t < 2 * X_) xt[t >> 6][t & 63] = 0.f;  // GO token
  __syncthreads();

  for (int i = 0; i < T_; ++i) {
    const float m0 = (float)mask0[i];
    const float m1 = (float)mask1[i];
    const int pg = (i < skip) ? 2 * i : i - skip;
    bool gzf = pg < skip;
    int gidx = pg - skip;
    if (gidx < 0) gidx = 0;
    if (gidx >= i) gzf = true;  // unwritten slot == reference's zero init
    const int ppos = (i < skip) ? 2 * i + 1 : i - skip;
    const bool pzf = ppos < skip;
    int pidx = ppos - skip;
    if (pidx < 0) pidx = 0;

    // ---- phase 0: masked hidden (per-column, all LDS/own data) ----
    float hp0 = (i == 0) ? h_enc[(size_t)b0 * H_ + t] : ring[0][(i - 1) & (RS - 1)][t];
    float hp1 = (i == 0) ? h_enc[(size_t)(b0 + 1) * H_ + t] : ring[1][(i - 1) & (RS - 1)][t];
    float sg0 = gzf ? 0.f : ring[0][gidx & (RS - 1)][t];
    float sg1 = gzf ? 0.f : ring[1][gidx & (RS - 1)][t];
    float hid0 = m0 * hp0 + m1 * sg0;
    float hid1 = m0 * hp1 + m1 * sg1;
    hid[0][t] = hid0;
    hid[1][t] = hid1;
    __syncthreads();

    // ---- phase 1: gates.  Weight loads: 64 lanes contiguous (k4-major). ----
    float ar0 = 0, az0 = 0, an0 = 0, ar1 = 0, az1 = 0, an1 = 0;
    {
      const float4* h40 = (const float4*)hid[0];
      const float4* h41 = (const float4*)hid[1];
      const float4* w = Thh + t;
#pragma unroll 4
      for (int k4 = 0; k4 < H_ / 4; ++k4) {
        float4 wr = w[0], wz = w[256], wn = w[512];
        float4 h0 = h40[k4], h1 = h41[k4];
        ar0 = dot4(h0, wr, ar0); az0 = dot4(h0, wz, az0); an0 = dot4(h0, wn, an0);
        ar1 = dot4(h1, wr, ar1); az1 = dot4(h1, wz, az1); an1 = dot4(h1, wn, an1);
        w += 768;
      }
    }
    float gr0 = 0, gz0 = 0, gn0 = 0, gr1 = 0, gz1 = 0, gn1 = 0;
    {
      const float4* x40 = (const float4*)xt[0];
      const float4* x41 = (const float4*)xt[1];
      const float4* w = Tih + t;
#pragma unroll
      for (int k4 = 0; k4 < X_ / 4; ++k4) {
        float4 wr = w[0], wz = w[256], wn = w[512];
        float4 x0 = x40[k4], x1 = x41[k4];
        gr0 = dot4(x0, wr, gr0); gz0 = dot4(x0, wz, gz0); gn0 = dot4(x0, wn, gn0);
        gr1 = dot4(x1, wr, gr1); gz1 = dot4(x1, wz, gz1); gn1 = dot4(x1, wn, gn1);
        w += 768;
      }
    }
    float r0 = sigmoid_f(gr0 + ar0 + bsr);
    float z0 = sigmoid_f(gz0 + az0 + bsz);
    float n0 = tanh_f((gn0 + bin_) + r0 * (an0 + bhn_));
    float hn0 = fmaf(z0, hid0 - n0, n0);  // (1-z)*n + z*hidden
    float r1 = sigmoid_f(gr1 + ar1 + bsr);
    float z1 = sigmoid_f(gz1 + az1 + bsz);
    float n1 = tanh_f((gn1 + bin_) + r1 * (an1 + bhn_));
    float hn1 = fmaf(z1, hid1 - n1, n1);
    ring[0][i & (RS - 1)][t] = hn0;
    ring[1][i & (RS - 1)][t] = hn1;
    float sp0, sp1;
    if (pzf) {
      sp0 = 0.f; sp1 = 0.f;
    } else if (pidx == i) {     // i == skip-1: same-step h_new, in-register
      sp0 = hn0; sp1 = hn1;
    } else {
      sp0 = ring[0][pidx & (RS - 1)][t];
      sp1 = ring[1][pidx & (RS - 1)][t];
    }
    pt[0][t] = hp0 + sp0;
    pt[1][t] = hp1 + sp1;
    __syncthreads();

    // ---- phase 2a: projection partials (all 4 waves, k split in halves) ----
    {
      int q = t >> 7, bj = (t >> 6) & 1, col = t & 63;
      const float4* p4 = ((const float4*)pt[bj]) + q * 32;
      const float4* w = Tou + q * 32 * 64 + col;
      float acc = 0.f;
#pragma unroll 8
      for (int k4 = 0; k4 < 32; ++k4) {
        acc = dot4(p4[k4], w[0], acc);
        w += 64;
      }
      pp[q][bj][col] = acc;
    }
    __syncthreads();
    if (t < 2 * X_) {
      int bj = t >> 6, col = t & 63;
      float o = pp[0][bj][col] + pp[1][bj][col] + b_out[col];
      out[(size_t)(b0 + bj) * T_ * X_ + (size_t)i * X_ + col] = o;
      xt[bj][col] = o;  // feedback for next step
    }
    __syncthreads();
  }
}

extern "C" void kernel_launch(void* const* d_in, const int* in_sizes, int n_in,
                              void* d_out, int out_size, void* d_ws,
                              size_t ws_size, hipStream_t stream) {
  (void)in_sizes; (void)n_in; (void)out_size; (void)ws_size;
  // d_in[0] = input [B,T,X] — unused by the reference computation.
  const float* h_enc = (const float*)d_in[1];
  const float4* W_ih = (const float4*)d_in[2];
  const float4* W_hh = (const float4*)d_in[3];
  const float* b_ih = (const float*)d_in[4];
  const float* b_hh = (const float*)d_in[5];
  const float4* W_out = (const float4*)d_in[6];
  const float* b_out = (const float*)d_in[7];
  const int* mask0 = (const int*)d_in[8];
  const int* mask1 = (const int*)d_in[9];
  const int* skipp = (const int*)d_in[10];
  float* out = (float*)d_out;
  float4* T = (float4*)d_ws;  // 1 MB transposed weights

  prep_kernel<<<dim3(F4_TOTAL / NT), dim3(NT), 0, stream>>>(W_ih, W_hh, W_out, T);
  decoder_kernel<<<dim3(NWG), dim3(NT), 0, stream>>>(
      h_enc, b_ih, b_hh, b_out, mask0, mask1, skipp, T, out);
}

// Round 4
// 4492.632 us; speedup vs baseline: 3.1475x; 1.9495x over previous
//
#include <hip/hip_runtime.h>

// Decoder GRU, B=128 T=512 X=64 H=256, skip=4 (runtime).
// Round 4: fix occupancy.  64 WGs x 1024 thr (16 waves = 4/SIMD); each WG
// owns 2 batches end-to-end, all recurrent state in LDS, zero inter-WG
// communication.  Gate GEMM splits K 4-ways across thread groups (kq = t>>8),
// partials reduced through LDS; projection splits K 8-ways.  Weights streamed
// from XCD L2 in k4-major layout (prep kernel transpose) -> every weight load
// is 64 lanes x 16 B contiguous.  4 waves/SIMD hide the L2 latency that
// bounded round 3 (1 wave/SIMD, VALUBusy 8.8%).
constexpr int B_ = 128;
constexpr int T_ = 512;
constexpr int X_ = 64;
constexpr int H_ = 256;
constexpr int NWG = 64;    // 2 batches per WG
constexpr int NT = 1024;   // 16 waves
constexpr int RS = 16;     // ring slots; lookback 2*skip, OK for skip <= 7

constexpr int F4_HH = 64 * 768;   // 49152 float4 (768 KB)
constexpr int F4_IH = 16 * 768;   // 12288 float4 (192 KB)
constexpr int F4_OUT = 64 * 64;   //  4096 float4 (64 KB)
constexpr int F4_TOTAL = F4_HH + F4_IH + F4_OUT;  // 65536 -> 1 MB in d_ws

__device__ __forceinline__ float sigmoid_f(float x) {
  float e = __expf(fminf(-x, 80.f));
  return 1.f / (1.f + e);
}
__device__ __forceinline__ float tanh_f(float x) {
  float e = __expf(fminf(-2.f * x, 80.f));
  return (1.f - e) / (1.f + e);
}
__device__ __forceinline__ float dot4(float4 a, float4 b, float acc) {
  acc = fmaf(a.x, b.x, acc);
  acc = fmaf(a.y, b.y, acc);
  acc = fmaf(a.z, b.z, acc);
  acc = fmaf(a.w, b.w, acc);
  return acc;
}

// One-time layout transform: T_hh[k4*768 + r] = W_hh[r][4k4..4k4+3], etc.
__global__ void prep_kernel(const float4* __restrict__ Wih,
                            const float4* __restrict__ Whh,
                            const float4* __restrict__ Wout,
                            float4* __restrict__ T) {
  int id = blockIdx.x * 256 + threadIdx.x;
  if (id < F4_HH) {
    int k4 = id / 768, r = id - k4 * 768;
    T[id] = Whh[r * (H_ / 4) + k4];
  } else if (id < F4_HH + F4_IH) {
    int j = id - F4_HH;
    int k4 = j / 768, r = j - k4 * 768;
    T[id] = Wih[r * (X_ / 4) + k4];
  } else if (id < F4_TOTAL) {
    int j = id - F4_HH - F4_IH;
    int k4 = j >> 6, c = j & 63;
    T[id] = Wout[c * (H_ / 4) + k4];
  }
}

__global__ __launch_bounds__(NT, 1) void decoder_kernel(
    const float* __restrict__ h_enc, const float* __restrict__ b_ih,
    const float* __restrict__ b_hh, const float* __restrict__ b_out,
    const int* __restrict__ mask0, const int* __restrict__ mask1,
    const int* __restrict__ skipp, const float4* __restrict__ T,
    float* __restrict__ out) {
  __shared__ float ring[2][RS][H_];              // 32 KB WG-private h history
  __shared__ alignas(16) float hid[2][H_];       // masked hidden (GRU input)
  __shared__ float hps[2][H_];                   // h_prev stash (for pt)
  __shared__ alignas(16) float pt[2][H_];        // h_prev + skip_p
  __shared__ alignas(16) float xt[2][X_];        // x feedback (prev out row)
  __shared__ float part[4][8][H_];               // 32 KB gate partials
  __shared__ float pp[8][2][X_];                 // 4 KB projection partials

  const int t = threadIdx.x;
  const int col = t & 255;   // h column (phase 1)
  const int kq = t >> 8;     // K quarter (phase 1)
  const int b0 = blockIdx.x * 2;
  const int skip = skipp[0];
  const float4* Thh = T;
  const float4* Tih = T + F4_HH;
  const float4* Tou = T + F4_HH + F4_IH;

  // biases for phase-2 threads (t<512: b=t>>8, col=t&255)
  float bsr = 0, bsz = 0, bin_ = 0, bhn_ = 0;
  if (t < 512) {
    bsr = b_ih[col] + b_hh[col];
    bsz = b_ih[H_ + col] + b_hh[H_ + col];
    bin_ = b_ih[2 * H_ + col];
    bhn_ = b_hh[2 * H_ + col];
  }

  if (t < 2 * X_) xt[t >> 6][t & 63] = 0.f;  // GO token
  __syncthreads();

  for (int i = 0; i < T_; ++i) {
    const float m0 = (float)mask0[i];
    const float m1 = (float)mask1[i];
    const int pg = (i < skip) ? 2 * i : i - skip;
    bool gzf = pg < skip;
    int gidx = pg - skip;
    if (gidx < 0) gidx = 0;
    if (gidx >= i) gzf = true;  // unwritten slot == reference's zero init
    const int ppos = (i < skip) ? 2 * i + 1 : i - skip;
    const bool pzf = ppos < skip;
    int pidx = ppos - skip;
    if (pidx < 0) pidx = 0;

    // ---- phase 0: masked hidden (t<512: one (b,col) each) ----
    if (t < 512) {
      int b = t >> 8;
      float hp = (i == 0) ? h_enc[(size_t)(b0 + b) * H_ + col]
                          : ring[b][(i - 1) & (RS - 1)][col];
      float sg = gzf ? 0.f : ring[b][gidx & (RS - 1)][col];
      hps[b][col] = hp;
      hid[b][col] = m0 * hp + m1 * sg;
    }
    __syncthreads();

    // ---- phase 1: gate partials, K split 4 ways (all 1024 threads) ----
    float ar0 = 0, az0 = 0, ani0 = 0, anh0 = 0;
    float ar1 = 0, az1 = 0, ani1 = 0, anh1 = 0;
    {
      const float4* h40 = (const float4*)hid[0];
      const float4* h41 = (const float4*)hid[1];
      const float4* w = Thh + (size_t)(kq * 16) * 768 + col;
#pragma unroll 4
      for (int j = 0; j < 16; ++j) {
        float4 wr = w[0], wz = w[256], wn = w[512];
        float4 a0 = h40[kq * 16 + j], a1 = h41[kq * 16 + j];
        ar0 = dot4(a0, wr, ar0); az0 = dot4(a0, wz, az0); anh0 = dot4(a0, wn, anh0);
        ar1 = dot4(a1, wr, ar1); az1 = dot4(a1, wz, az1); anh1 = dot4(a1, wn, anh1);
        w += 768;
      }
    }
    {
      const float4* x40 = (const float4*)xt[0];
      const float4* x41 = (const float4*)xt[1];
      const float4* w = Tih + (size_t)(kq * 4) * 768 + col;
#pragma unroll
      for (int j = 0; j < 4; ++j) {
        float4 wr = w[0], wz = w[256], wn = w[512];
        float4 x0 = x40[kq * 4 + j], x1 = x41[kq * 4 + j];
        ar0 = dot4(x0, wr, ar0); az0 = dot4(x0, wz, az0); ani0 = dot4(x0, wn, ani0);
        ar1 = dot4(x1, wr, ar1); az1 = dot4(x1, wz, az1); ani1 = dot4(x1, wn, ani1);
        w += 768;
      }
    }
    part[kq][0][col] = ar0;  part[kq][1][col] = az0;
    part[kq][2][col] = ani0; part[kq][3][col] = anh0;
    part[kq][4][col] = ar1;  part[kq][5][col] = az1;
    part[kq][6][col] = ani1; part[kq][7][col] = anh1;
    __syncthreads();

    // ---- phase 2: finalize gates (t<512: one (b,col) each) ----
    if (t < 512) {
      int b = t >> 8;
      int j0 = b * 4;
      float sr = part[0][j0][col] + part[1][j0][col] + part[2][j0][col] + part[3][j0][col];
      float sz = part[0][j0 + 1][col] + part[1][j0 + 1][col] + part[2][j0 + 1][col] + part[3][j0 + 1][col];
      float sni = part[0][j0 + 2][col] + part[1][j0 + 2][col] + part[2][j0 + 2][col] + part[3][j0 + 2][col];
      float snh = part[0][j0 + 3][col] + part[1][j0 + 3][col] + part[2][j0 + 3][col] + part[3][j0 + 3][col];
      float r = sigmoid_f(sr + bsr);
      float z = sigmoid_f(sz + bsz);
      float n = tanh_f((sni + bin_) + r * (snh + bhn_));
      float hv = hid[b][col];
      float hn = fmaf(z, hv - n, n);  // (1-z)*n + z*hidden
      ring[b][i & (RS - 1)][col] = hn;
      float sp;
      if (pzf) sp = 0.f;
      else if (pidx == i) sp = hn;           // i == skip-1: same-step h_new
      else sp = ring[b][pidx & (RS - 1)][col];
      pt[b][col] = hps[b][col] + sp;
    }
    __syncthreads();

    // ---- phase 3: projection partials, K split 8 ways (all threads) ----
    {
      int xcol = t & 63, bj = (t >> 6) & 1, k8 = t >> 7;
      const float4* p4 = (const float4*)pt[bj];
      const float4* w = Tou + (size_t)(k8 * 8) * 64 + xcol;
      float acc = 0.f;
#pragma unroll
      for (int j = 0; j < 8; ++j) {
        acc = dot4(p4[k8 * 8 + j], w[0], acc);
        w += 64;
      }
      pp[k8][bj][xcol] = acc;
    }
    __syncthreads();

    // ---- phase 4: finalize out + feedback (t<128) ----
    if (t < 128) {
      int bj = t >> 6, xcol = t & 63;
      float o = pp[0][bj][xcol] + pp[1][bj][xcol] + pp[2][bj][xcol] +
                pp[3][bj][xcol] + pp[4][bj][xcol] + pp[5][bj][xcol] +
                pp[6][bj][xcol] + pp[7][bj][xcol] + b_out[xcol];
      out[(size_t)(b0 + bj) * T_ * X_ + (size_t)i * X_ + xcol] = o;
      xt[bj][xcol] = o;  // feedback for next step
    }
    __syncthreads();
  }
}

extern "C" void kernel_launch(void* const* d_in, const int* in_sizes, int n_in,
                              void* d_out, int out_size, void* d_ws,
                              size_t ws_size, hipStream_t stream) {
  (void)in_sizes; (void)n_in; (void)out_size; (void)ws_size;
  // d_in[0] = input [B,T,X] — unused by the reference computation.
  const float* h_enc = (const float*)d_in[1];
  const float4* W_ih = (const float4*)d_in[2];
  const float4* W_hh = (const float4*)d_in[3];
  const float* b_ih = (const float*)d_in[4];
  const float* b_hh = (const float*)d_in[5];
  const float4* W_out = (const float4*)d_in[6];
  const float* b_out = (const float*)d_in[7];
  const int* mask0 = (const int*)d_in[8];
  const int* mask1 = (const int*)d_in[9];
  const int* skipp = (const int*)d_in[10];
  float* out = (float*)d_out;
  float4* T = (float4*)d_ws;  // 1 MB transposed weights

  prep_kernel<<<dim3(F4_TOTAL / 256), dim3(256), 0, stream>>>(W_ih, W_hh, W_out, T);
  decoder_kernel<<<dim3(NWG), dim3(NT), 0, stream>>>(
      h_enc, b_ih, b_hh, b_out, mask0, mask1, skipp, T, out);
}